// Round 6
// baseline (71999.878 us; speedup 1.0000x reference)
//
#include <hip/hip_runtime.h>
#include <hip/hip_bf16.h>
#include <stdint.h>

#define NB    256
#define LSEQ  1024
#define CINC  16
#define SSTEP 128
#define HDIM  256
#define NLAY  6
#define H3    768
#define SPB   4          // samples per block
#define NBLK  (NB/SPB)   // 64 blocks

__device__ __forceinline__ float sigm(float x){ return 1.f/(1.f+__expf(-x)); }
__device__ __forceinline__ float tanh_(float x){ float e=__expf(2.f*x); return 1.f - 2.f/(e+1.f); }

// shuffle write-position: element with flat index o of a [4][128] tensor goes to
// position pi(o) so the NEXT consumer can read contiguously.
__device__ __forceinline__ int shufpos(int o){
    return (((o >> 5) & 3) << 7) | ((o & 31) << 2) | (o >> 7);
}

__global__ __launch_bounds__(1024)
void encoder_kernel(const float* __restrict__ x,
                    const float* __restrict__ Wih0, const float* __restrict__ WihR,
                    const float* __restrict__ Whh,  const float* __restrict__ bih,
                    const float* __restrict__ bhh,  const float* __restrict__ h0,
                    const float* __restrict__ aW1,  const float* __restrict__ aW2,
                    const float* __restrict__ aW3,  const float* __restrict__ aW4,
                    float* __restrict__ enc)
{
    const int b0  = blockIdx.x * SPB;
    const int tid = threadIdx.x;
    const int j   = tid >> 2;    // feature / output 0..255
    const int s   = tid & 3;     // sample 0..3  (4 lanes share weight rows)

    // per-sample strides padded so the 4 samples' streams hit distinct banks
    __shared__ __align__(16) float h   [SPB][NLAY][264];
    __shared__ __align__(16) float inp [SPB][264];
    __shared__ __align__(16) float hnew[SPB][264];
    __shared__ __align__(16) float hs  [SPB][264];
    __shared__ __align__(16) float a1s [SPB][520];   // shuffled for a2
    __shared__ __align__(16) float a2s [SPB][520];   // shuffled for a3
    __shared__ __align__(16) float a3f [SPB][520];   // flat for a4

    for (int idx = tid; idx < SPB*NLAY*HDIM; idx += 1024) {
        int ss = idx / (NLAY*HDIM), rem = idx % (NLAY*HDIM);
        h[ss][rem >> 8][rem & 255] = h0[rem];
    }

    for (int t = 0; t < SSTEP; ++t) {
        if (tid < SPB*128) {
            int ss = tid >> 7, off = tid & 127;
            inp[ss][off] = x[(size_t)(b0+ss)*(LSEQ*CINC) + (size_t)t*128 + off];
        }
        __syncthreads();

        for (int l = 0; l < NLAY; ++l) {
            const float* whh = Whh + (size_t)l*H3*HDIM;

            // ---- GRU: thread (j,s) computes feature j of sample s.
            // Each activation float4 is loaded once and reused for 3 gate rows.
            {
                float r0=0.f,r1=0.f,r2=0.f, q0=0.f,q1=0.f,q2=0.f;
                if (l == 0) {
                    const float4* ip4 = (const float4*)inp[s];
                    const float4* w0 = (const float4*)(Wih0 + (size_t)(j      )*128);
                    const float4* w1 = (const float4*)(Wih0 + (size_t)(j + 256)*128);
                    const float4* w2 = (const float4*)(Wih0 + (size_t)(j + 512)*128);
                    #pragma unroll 4
                    for (int i = 0; i < 32; ++i) {
                        float4 A = ip4[i];
                        float4 W0 = w0[i], W1 = w1[i], W2 = w2[i];
                        r0 += A.x*W0.x + A.y*W0.y + A.z*W0.z + A.w*W0.w;
                        r1 += A.x*W1.x + A.y*W1.y + A.z*W1.z + A.w*W1.w;
                        r2 += A.x*W2.x + A.y*W2.y + A.z*W2.z + A.w*W2.w;
                    }
                } else {
                    const float* wih = WihR + (size_t)(l-1)*H3*HDIM;
                    const float4* ip4 = (const float4*)inp[s];
                    const float4* w0 = (const float4*)(wih + (size_t)(j      )*HDIM);
                    const float4* w1 = (const float4*)(wih + (size_t)(j + 256)*HDIM);
                    const float4* w2 = (const float4*)(wih + (size_t)(j + 512)*HDIM);
                    #pragma unroll 4
                    for (int i = 0; i < 64; ++i) {
                        float4 A = ip4[i];
                        float4 W0 = w0[i], W1 = w1[i], W2 = w2[i];
                        r0 += A.x*W0.x + A.y*W0.y + A.z*W0.z + A.w*W0.w;
                        r1 += A.x*W1.x + A.y*W1.y + A.z*W1.z + A.w*W1.w;
                        r2 += A.x*W2.x + A.y*W2.y + A.z*W2.z + A.w*W2.w;
                    }
                }
                {
                    const float4* hp4 = (const float4*)h[s][l];
                    const float4* v0 = (const float4*)(whh + (size_t)(j      )*HDIM);
                    const float4* v1 = (const float4*)(whh + (size_t)(j + 256)*HDIM);
                    const float4* v2 = (const float4*)(whh + (size_t)(j + 512)*HDIM);
                    #pragma unroll 4
                    for (int i = 0; i < 64; ++i) {
                        float4 A = hp4[i];
                        float4 W0 = v0[i], W1 = v1[i], W2 = v2[i];
                        q0 += A.x*W0.x + A.y*W0.y + A.z*W0.z + A.w*W0.w;
                        q1 += A.x*W1.x + A.y*W1.y + A.z*W1.z + A.w*W1.w;
                        q2 += A.x*W2.x + A.y*W2.y + A.z*W2.z + A.w*W2.w;
                    }
                }
                float gr = r0 + q0 + bih[l*H3 + j]       + bhh[l*H3 + j];
                float gz = r1 + q1 + bih[l*H3 + 256 + j] + bhh[l*H3 + 256 + j];
                float gi = r2 + bih[l*H3 + 512 + j];   // i_n, kept separate
                float gh = q2 + bhh[l*H3 + 512 + j];   // h_n
                float r = sigm(gr), z = sigm(gz);
                float n = tanh_(gi + r*gh);
                hnew[s][j] = (1.f - z)*n + z*h[s][l][j];
            }
            __syncthreads();

            // ---- ascending rank-sort of hnew[s] (stable: ties by index)
            {
                float hv = hnew[s][j];
                int rank = 0;
                const float4* hp = (const float4*)hnew[s];
                #pragma unroll 8
                for (int k4 = 0; k4 < 64; ++k4) {
                    float4 u = hp[k4];
                    int k = 4*k4;
                    rank += (u.x < hv) || (u.x == hv && (k  ) < j);
                    rank += (u.y < hv) || (u.y == hv && (k+1) < j);
                    rank += (u.z < hv) || (u.z == hv && (k+2) < j);
                    rank += (u.w < hv) || (u.w == hv && (k+3) < j);
                }
                hs[s][rank] = hv;
            }
            __syncthreads();

            // ---- a1 = se @ W1^T (se = [hnew, hs]); store shuffled for a2
            {
                const float4* w4  = (const float4*)(aW1 + (size_t)l*65536 + (size_t)j*HDIM);
                const float4* hp4 = (const float4*)hnew[s];
                const float4* sp4 = (const float4*)hs[s];
                float acc0 = 0.f, acc1 = 0.f;
                #pragma unroll 4
                for (int i = 0; i < 64; ++i) {
                    float4 W = w4[i], P = hp4[i], Q = sp4[i];
                    acc0 += P.x*W.x + P.y*W.y + P.z*W.z + P.w*W.w;
                    acc1 += Q.x*W.x + Q.y*W.y + Q.z*W.z + Q.w*W.w;
                }
                a1s[s][shufpos(j)]       = acc0;
                a1s[s][shufpos(256 + j)] = acc1;
            }
            __syncthreads();

            // ---- a2 = shuf(a1) @ W2^T ; reads contiguous, store shuffled
            #pragma unroll
            for (int rep = 0; rep < 2; ++rep) {
                int o = rep*256 + j;          // 0..511
                int g = o >> 7, m = o & 127;
                const float4* w4  = (const float4*)(aW2 + (size_t)l*16384 + (size_t)m*128);
                const float4* act = (const float4*)(&a1s[s][g << 7]);
                float acc = 0.f;
                #pragma unroll 4
                for (int i = 0; i < 32; ++i) {
                    float4 W = w4[i], A = act[i];
                    acc += A.x*W.x + A.y*W.y + A.z*W.z + A.w*W.w;
                }
                a2s[s][shufpos(o)] = acc;
            }
            __syncthreads();

            // ---- a3 = relu( shuf(a2) @ W3^T ) ; store flat for a4
            #pragma unroll
            for (int rep = 0; rep < 2; ++rep) {
                int o = rep*256 + j;
                int g = o >> 7, m = o & 127;
                const float4* w4  = (const float4*)(aW3 + (size_t)l*16384 + (size_t)m*128);
                const float4* act = (const float4*)(&a2s[s][g << 7]);
                float acc = 0.f;
                #pragma unroll 4
                for (int i = 0; i < 32; ++i) {
                    float4 W = w4[i], A = act[i];
                    acc += A.x*W.x + A.y*W.y + A.z*W.z + A.w*W.w;
                }
                a3f[s][o] = fmaxf(acc, 0.f);
            }
            __syncthreads();

            // ---- a4 = a3(flat 512) @ W4^T ; h_out = hnew * sigmoid(a4)
            {
                const float4* w4  = (const float4*)(aW4 + (size_t)l*131072 + (size_t)j*512);
                const float4* act = (const float4*)a3f[s];
                float acc = 0.f;
                #pragma unroll 4
                for (int i = 0; i < 128; ++i) {
                    float4 W = w4[i], A = act[i];
                    acc += A.x*W.x + A.y*W.y + A.z*W.z + A.w*W.w;
                }
                float ho = hnew[s][j] * sigm(acc);
                h[s][l][j] = ho;
                inp[s][j]  = ho;
                if (l == NLAY-1)
                    enc[((size_t)(b0+s)*SSTEP + t)*HDIM + j] = ho;
            }
            __syncthreads();
        }
    }
}

// ---------------- decoders (unchanged, negligible cost) ----------------

__global__ __launch_bounds__(256)
void seqdec_kernel(const float* __restrict__ enc,
                   const float* __restrict__ W1, const float* __restrict__ b1,
                   const float* __restrict__ W2, const float* __restrict__ b2,
                   const float* __restrict__ W3, const float* __restrict__ b3,
                   const float* __restrict__ W4, const float* __restrict__ b4,
                   float* __restrict__ yseq)
{
    int idx = blockIdx.x*blockDim.x + threadIdx.x;
    if (idx >= NB*SSTEP) return;
    int b = idx >> 7, s = idx & 127;
    const float* e = enc + (size_t)idx*HDIM;

    float A[8][4], Bm[8][4], Cm[8][4];
    #pragma unroll
    for (int g = 0; g < 8; ++g)
      #pragma unroll
      for (int o = 0; o < 4; ++o) {
        float acc = b1[o];
        for (int k = 0; k < 32; ++k) acc += e[g*32+k] * W1[o*32+k];
        A[g][o] = acc;
      }
    #pragma unroll
    for (int r = 0; r < 8; ++r)
      #pragma unroll
      for (int c = 0; c < 4; ++c) {
        float acc = b2[c];
        #pragma unroll
        for (int q = 0; q < 4; ++q)
            acc += A[(4*r+q)&7][(4*r+q)>>3] * W2[c*4+q];
        Bm[r][c] = acc;
      }
    #pragma unroll
    for (int r = 0; r < 8; ++r)
      #pragma unroll
      for (int c = 0; c < 4; ++c) {
        float acc = b3[c];
        #pragma unroll
        for (int q = 0; q < 4; ++q)
            acc += Bm[(4*r+q)&7][(4*r+q)>>3] * W3[c*4+q];
        Cm[r][c] = acc;
      }
    #pragma unroll
    for (int o = 0; o < 4; ++o)
      #pragma unroll
      for (int w = 0; w < 8; ++w) {
        float acc = b4[w];
        #pragma unroll
        for (int g = 0; g < 8; ++g)
            acc += Cm[(o*8+g)>>2][(o*8+g)&3] * W4[w*8+g];
        yseq[((size_t)b*LSEQ + s*8 + w)*4 + o] = acc;
      }
}

__global__ __launch_bounds__(64)
void onedec_kernel(const float* __restrict__ enc,
                   const float* __restrict__ W1, const float* __restrict__ b1,
                   const float* __restrict__ W2, const float* __restrict__ b2,
                   const float* __restrict__ W3, const float* __restrict__ b3,
                   const float* __restrict__ W4, const float* __restrict__ b4,
                   float* __restrict__ yone)
{
    int b = blockIdx.x;
    int tid = threadIdx.x;
    __shared__ float part[10][4];
    if (tid < 10) {
        int s = SSTEP - 10 + tid;
        const float* e = enc + ((size_t)b*SSTEP + s)*HDIM;
        float A[8][4], Bm[8][4], Cm[8][4];
        #pragma unroll
        for (int g = 0; g < 8; ++g)
          #pragma unroll
          for (int o = 0; o < 4; ++o) {
            float acc = b1[o];
            for (int k = 0; k < 32; ++k) acc += e[g*32+k] * W1[o*32+k];
            A[g][o] = acc;
          }
        #pragma unroll
        for (int r = 0; r < 8; ++r)
          #pragma unroll
          for (int c = 0; c < 4; ++c) {
            float acc = b2[c];
            #pragma unroll
            for (int q = 0; q < 4; ++q)
                acc += A[(4*r+q)&7][(4*r+q)>>3] * W2[c*4+q];
            Bm[r][c] = acc;
          }
        #pragma unroll
        for (int r = 0; r < 8; ++r)
          #pragma unroll
          for (int c = 0; c < 4; ++c) {
            float acc = b3[c];
            #pragma unroll
            for (int q = 0; q < 4; ++q)
                acc += Bm[(4*r+q)&7][(4*r+q)>>3] * W3[c*4+q];
            Cm[r][c] = fmaxf(acc, 0.f);   // relu
          }
        #pragma unroll
        for (int jj = 0; jj < 4; ++jj) {
            float acc = b4[jj];
            #pragma unroll
            for (int m = 0; m < 32; ++m)
                acc += Cm[m>>2][m&3] * W4[jj*32+m];
            part[tid][jj] = sigm(acc);
        }
    }
    __syncthreads();
    if (tid < 4) {
        float acc = 0.f;
        #pragma unroll
        for (int k = 0; k < 10; ++k) acc += part[k][tid];
        yone[b*4 + tid] = acc * 0.1f;
    }
}

extern "C" void kernel_launch(void* const* d_in, const int* in_sizes, int n_in,
                              void* d_out, int out_size, void* d_ws, size_t ws_size,
                              hipStream_t stream)
{
    const float* x    = (const float*)d_in[0];
    const float* Wih0 = (const float*)d_in[1];
    const float* WihR = (const float*)d_in[2];
    const float* Whh  = (const float*)d_in[3];
    const float* bih  = (const float*)d_in[4];
    const float* bhh  = (const float*)d_in[5];
    const float* h0   = (const float*)d_in[6];
    const float* aW1  = (const float*)d_in[7];
    const float* aW2  = (const float*)d_in[8];
    const float* aW3  = (const float*)d_in[9];
    const float* aW4  = (const float*)d_in[10];
    const float* sdW1 = (const float*)d_in[11];
    const float* sdb1 = (const float*)d_in[12];
    const float* sdW2 = (const float*)d_in[13];
    const float* sdb2 = (const float*)d_in[14];
    const float* sdW3 = (const float*)d_in[15];
    const float* sdb3 = (const float*)d_in[16];
    const float* sdW4 = (const float*)d_in[17];
    const float* sdb4 = (const float*)d_in[18];
    const float* odW1 = (const float*)d_in[19];
    const float* odb1 = (const float*)d_in[20];
    const float* odW2 = (const float*)d_in[21];
    const float* odb2 = (const float*)d_in[22];
    const float* odW3 = (const float*)d_in[23];
    const float* odb3 = (const float*)d_in[24];
    const float* odW4 = (const float*)d_in[25];
    const float* odb4 = (const float*)d_in[26];

    float* out  = (float*)d_out;
    float* enc  = out;                                   // [256][128][256]
    float* yseq = out + (size_t)NB*SSTEP*HDIM;           // [256][1024][4]
    float* yone = yseq + (size_t)NB*LSEQ*4;              // [256][4]

    hipLaunchKernelGGL(encoder_kernel, dim3(NBLK), dim3(1024), 0, stream,
                       x, Wih0, WihR, Whh, bih, bhh, h0, aW1, aW2, aW3, aW4, enc);
    hipLaunchKernelGGL(seqdec_kernel, dim3((NB*SSTEP)/256), dim3(256), 0, stream,
                       enc, sdW1, sdb1, sdW2, sdb2, sdW3, sdb3, sdW4, sdb4, yseq);
    hipLaunchKernelGGL(onedec_kernel, dim3(NB), dim3(64), 0, stream,
                       enc, odW1, odb1, odW2, odb2, odW3, odb3, odW4, odb4, yone);
}

// Round 7
// 38050.143 us; speedup vs baseline: 1.8922x; 1.8922x over previous
//
#include <hip/hip_runtime.h>
#include <hip/hip_bf16.h>
#include <stdint.h>

#define NB    256
#define LSEQ  1024
#define CINC  16
#define SSTEP 128
#define HDIM  256
#define NLAY  6
#define H3    768
#define SPB   2           // samples per block
#define NBLK  (NB/SPB)    // 128 blocks
#define TPB   512

typedef unsigned short u16;

// bf16 element counts of each repacked weight segment in d_ws
#define N_WIH0 (768*128)
#define N_WIHR (5*768*256)
#define N_WHH  (6*768*256)
#define N_AW1  (6*256*256)
#define N_AW2  (6*128*128)
#define N_AW3  (6*128*128)
#define N_AW4  (6*256*512)

__device__ __forceinline__ float sigm(float x){ return 1.f/(1.f+__expf(-x)); }
__device__ __forceinline__ float tanh_(float x){ float e=__expf(2.f*x); return 1.f - 2.f/(e+1.f); }
__device__ __forceinline__ float blo(uint32_t u){ return __uint_as_float(u << 16); }
__device__ __forceinline__ float bhi(uint32_t u){ return __uint_as_float(u & 0xffff0000u); }

// shuffle write-position: element o of a [4][128] tensor goes to pi(o) so the
// next consumer reads contiguously.
__device__ __forceinline__ int shufpos(int o){
    return (((o >> 5) & 3) << 7) | ((o & 31) << 2) | (o >> 7);
}

__global__ void repack_kernel(const float* __restrict__ src, u16* __restrict__ dst, int n)
{
    int i = blockIdx.x*blockDim.x + threadIdx.x;
    if (i < n) {
        uint32_t u = __float_as_uint(src[i]);
        uint32_t r = u + 0x7fffu + ((u >> 16) & 1u);   // RNE f32->bf16
        dst[i] = (u16)(r >> 16);
    }
}

// 512 threads: thread = (j, s), j = feature 0..255, s = sample 0..1.
__global__ __launch_bounds__(TPB)
void encoder_kernel(const float* __restrict__ x,
                    const u16* __restrict__ Wih0, const u16* __restrict__ WihR,
                    const u16* __restrict__ Whh,
                    const float* __restrict__ bih, const float* __restrict__ bhh,
                    const float* __restrict__ h0,
                    const u16* __restrict__ aW1,  const u16* __restrict__ aW2,
                    const u16* __restrict__ aW3,  const u16* __restrict__ aW4,
                    float* __restrict__ enc)
{
    const int b0  = blockIdx.x * SPB;
    const int tid = threadIdx.x;
    const int j   = tid >> 1;    // feature / output 0..255
    const int s   = tid & 1;     // sample 0..1 (lane pairs share weight rows)

    __shared__ __align__(16) float h   [SPB][NLAY][264];
    __shared__ __align__(16) float inp [SPB][264];
    __shared__ __align__(16) float hnew[SPB][264];
    __shared__ __align__(16) float hs  [SPB][264];
    __shared__ __align__(16) float a1s [SPB][520];   // shuffled for a2
    __shared__ __align__(16) float a2s [SPB][520];   // shuffled for a3
    __shared__ __align__(16) float a3f [SPB][520];   // flat for a4

    for (int idx = tid; idx < SPB*NLAY*HDIM; idx += TPB) {
        int ss = idx / (NLAY*HDIM), rem = idx % (NLAY*HDIM);
        h[ss][rem >> 8][rem & 255] = h0[rem];
    }

    for (int t = 0; t < SSTEP; ++t) {
        if (tid < SPB*128) {
            int ss = tid >> 7, off = tid & 127;
            inp[ss][off] = x[(size_t)(b0+ss)*(LSEQ*CINC) + (size_t)t*128 + off];
        }
        __syncthreads();

        for (int l = 0; l < NLAY; ++l) {
            // ---- GRU: thread (j,s) computes feature j of sample s.
            {
                float r0=0.f,r1=0.f,r2=0.f, q0=0.f,q1=0.f,q2=0.f;
                if (l == 0) {
                    const uint4* w0 = (const uint4*)(Wih0 + (size_t)(j      )*128);
                    const uint4* w1 = (const uint4*)(Wih0 + (size_t)(j + 256)*128);
                    const uint4* w2 = (const uint4*)(Wih0 + (size_t)(j + 512)*128);
                    const float4* ip4 = (const float4*)inp[s];
                    #pragma unroll 4
                    for (int i = 0; i < 16; ++i) {
                        uint4 u0 = w0[i], u1 = w1[i], u2 = w2[i];
                        float4 A0 = ip4[2*i], A1 = ip4[2*i+1];
                        r0 += A0.x*blo(u0.x)+A0.y*bhi(u0.x)+A0.z*blo(u0.y)+A0.w*bhi(u0.y)
                            + A1.x*blo(u0.z)+A1.y*bhi(u0.z)+A1.z*blo(u0.w)+A1.w*bhi(u0.w);
                        r1 += A0.x*blo(u1.x)+A0.y*bhi(u1.x)+A0.z*blo(u1.y)+A0.w*bhi(u1.y)
                            + A1.x*blo(u1.z)+A1.y*bhi(u1.z)+A1.z*blo(u1.w)+A1.w*bhi(u1.w);
                        r2 += A0.x*blo(u2.x)+A0.y*bhi(u2.x)+A0.z*blo(u2.y)+A0.w*bhi(u2.y)
                            + A1.x*blo(u2.z)+A1.y*bhi(u2.z)+A1.z*blo(u2.w)+A1.w*bhi(u2.w);
                    }
                } else {
                    const u16* wih = WihR + (size_t)(l-1)*H3*HDIM;
                    const uint4* w0 = (const uint4*)(wih + (size_t)(j      )*HDIM);
                    const uint4* w1 = (const uint4*)(wih + (size_t)(j + 256)*HDIM);
                    const uint4* w2 = (const uint4*)(wih + (size_t)(j + 512)*HDIM);
                    const float4* ip4 = (const float4*)inp[s];
                    #pragma unroll 4
                    for (int i = 0; i < 32; ++i) {
                        uint4 u0 = w0[i], u1 = w1[i], u2 = w2[i];
                        float4 A0 = ip4[2*i], A1 = ip4[2*i+1];
                        r0 += A0.x*blo(u0.x)+A0.y*bhi(u0.x)+A0.z*blo(u0.y)+A0.w*bhi(u0.y)
                            + A1.x*blo(u0.z)+A1.y*bhi(u0.z)+A1.z*blo(u0.w)+A1.w*bhi(u0.w);
                        r1 += A0.x*blo(u1.x)+A0.y*bhi(u1.x)+A0.z*blo(u1.y)+A0.w*bhi(u1.y)
                            + A1.x*blo(u1.z)+A1.y*bhi(u1.z)+A1.z*blo(u1.w)+A1.w*bhi(u1.w);
                        r2 += A0.x*blo(u2.x)+A0.y*bhi(u2.x)+A0.z*blo(u2.y)+A0.w*bhi(u2.y)
                            + A1.x*blo(u2.z)+A1.y*bhi(u2.z)+A1.z*blo(u2.w)+A1.w*bhi(u2.w);
                    }
                }
                {
                    const u16* whh = Whh + (size_t)l*H3*HDIM;
                    const uint4* v0 = (const uint4*)(whh + (size_t)(j      )*HDIM);
                    const uint4* v1 = (const uint4*)(whh + (size_t)(j + 256)*HDIM);
                    const uint4* v2 = (const uint4*)(whh + (size_t)(j + 512)*HDIM);
                    const float4* hp4 = (const float4*)h[s][l];
                    #pragma unroll 4
                    for (int i = 0; i < 32; ++i) {
                        uint4 u0 = v0[i], u1 = v1[i], u2 = v2[i];
                        float4 A0 = hp4[2*i], A1 = hp4[2*i+1];
                        q0 += A0.x*blo(u0.x)+A0.y*bhi(u0.x)+A0.z*blo(u0.y)+A0.w*bhi(u0.y)
                            + A1.x*blo(u0.z)+A1.y*bhi(u0.z)+A1.z*blo(u0.w)+A1.w*bhi(u0.w);
                        q1 += A0.x*blo(u1.x)+A0.y*bhi(u1.x)+A0.z*blo(u1.y)+A0.w*bhi(u1.y)
                            + A1.x*blo(u1.z)+A1.y*bhi(u1.z)+A1.z*blo(u1.w)+A1.w*bhi(u1.w);
                        q2 += A0.x*blo(u2.x)+A0.y*bhi(u2.x)+A0.z*blo(u2.y)+A0.w*bhi(u2.y)
                            + A1.x*blo(u2.z)+A1.y*bhi(u2.z)+A1.z*blo(u2.w)+A1.w*bhi(u2.w);
                    }
                }
                float gr = r0 + q0 + bih[l*H3 + j]       + bhh[l*H3 + j];
                float gz = r1 + q1 + bih[l*H3 + 256 + j] + bhh[l*H3 + 256 + j];
                float gi = r2 + bih[l*H3 + 512 + j];   // i_n, kept separate
                float gh = q2 + bhh[l*H3 + 512 + j];   // h_n
                float r = sigm(gr), z = sigm(gz);
                float n = tanh_(gi + r*gh);
                hnew[s][j] = (1.f - z)*n + z*h[s][l][j];
            }
            __syncthreads();

            // ---- ascending rank-sort of hnew[s] (stable: ties by index)
            {
                float hv = hnew[s][j];
                int rank = 0;
                const float4* hp = (const float4*)hnew[s];
                #pragma unroll 8
                for (int k4 = 0; k4 < 64; ++k4) {
                    float4 u = hp[k4];
                    int k = 4*k4;
                    rank += (u.x < hv) || (u.x == hv && (k  ) < j);
                    rank += (u.y < hv) || (u.y == hv && (k+1) < j);
                    rank += (u.z < hv) || (u.z == hv && (k+2) < j);
                    rank += (u.w < hv) || (u.w == hv && (k+3) < j);
                }
                hs[s][rank] = hv;
            }
            __syncthreads();

            // ---- a1 = se @ W1^T (se = [hnew, hs]); store shuffled for a2
            {
                const uint4* w4  = (const uint4*)(aW1 + (size_t)l*65536 + (size_t)j*HDIM);
                const float4* hp4 = (const float4*)hnew[s];
                const float4* sp4 = (const float4*)hs[s];
                float acc0 = 0.f, acc1 = 0.f;
                #pragma unroll 4
                for (int i = 0; i < 32; ++i) {
                    uint4 u = w4[i];
                    float w0=blo(u.x),w1=bhi(u.x),w2=blo(u.y),w3=bhi(u.y);
                    float w4_=blo(u.z),w5=bhi(u.z),w6=blo(u.w),w7=bhi(u.w);
                    float4 P0 = hp4[2*i], P1 = hp4[2*i+1];
                    float4 Q0 = sp4[2*i], Q1 = sp4[2*i+1];
                    acc0 += P0.x*w0+P0.y*w1+P0.z*w2+P0.w*w3 + P1.x*w4_+P1.y*w5+P1.z*w6+P1.w*w7;
                    acc1 += Q0.x*w0+Q0.y*w1+Q0.z*w2+Q0.w*w3 + Q1.x*w4_+Q1.y*w5+Q1.z*w6+Q1.w*w7;
                }
                a1s[s][shufpos(j)]       = acc0;
                a1s[s][shufpos(256 + j)] = acc1;
            }
            __syncthreads();

            // ---- a2 = shuf(a1) @ W2^T ; reads contiguous, store shuffled
            #pragma unroll
            for (int rep = 0; rep < 2; ++rep) {
                int o = rep*256 + j;          // 0..511
                int g = o >> 7, m = o & 127;
                const uint4* w4  = (const uint4*)(aW2 + (size_t)l*16384 + (size_t)m*128);
                const float4* act = (const float4*)(&a1s[s][g << 7]);
                float acc = 0.f;
                #pragma unroll 4
                for (int i = 0; i < 16; ++i) {
                    uint4 u = w4[i];
                    float4 A0 = act[2*i], A1 = act[2*i+1];
                    acc += A0.x*blo(u.x)+A0.y*bhi(u.x)+A0.z*blo(u.y)+A0.w*bhi(u.y)
                         + A1.x*blo(u.z)+A1.y*bhi(u.z)+A1.z*blo(u.w)+A1.w*bhi(u.w);
                }
                a2s[s][shufpos(o)] = acc;
            }
            __syncthreads();

            // ---- a3 = relu( shuf(a2) @ W3^T ) ; store flat for a4
            #pragma unroll
            for (int rep = 0; rep < 2; ++rep) {
                int o = rep*256 + j;
                int g = o >> 7, m = o & 127;
                const uint4* w4  = (const uint4*)(aW3 + (size_t)l*16384 + (size_t)m*128);
                const float4* act = (const float4*)(&a2s[s][g << 7]);
                float acc = 0.f;
                #pragma unroll 4
                for (int i = 0; i < 16; ++i) {
                    uint4 u = w4[i];
                    float4 A0 = act[2*i], A1 = act[2*i+1];
                    acc += A0.x*blo(u.x)+A0.y*bhi(u.x)+A0.z*blo(u.y)+A0.w*bhi(u.y)
                         + A1.x*blo(u.z)+A1.y*bhi(u.z)+A1.z*blo(u.w)+A1.w*bhi(u.w);
                }
                a3f[s][o] = fmaxf(acc, 0.f);
            }
            __syncthreads();

            // ---- a4 = a3(flat 512) @ W4^T ; h_out = hnew * sigmoid(a4)
            {
                const uint4* w4  = (const uint4*)(aW4 + (size_t)l*131072 + (size_t)j*512);
                const float4* act = (const float4*)a3f[s];
                float acc = 0.f;
                #pragma unroll 4
                for (int i = 0; i < 64; ++i) {
                    uint4 u = w4[i];
                    float4 A0 = act[2*i], A1 = act[2*i+1];
                    acc += A0.x*blo(u.x)+A0.y*bhi(u.x)+A0.z*blo(u.y)+A0.w*bhi(u.y)
                         + A1.x*blo(u.z)+A1.y*bhi(u.z)+A1.z*blo(u.w)+A1.w*bhi(u.w);
                }
                float ho = hnew[s][j] * sigm(acc);
                h[s][l][j] = ho;
                inp[s][j]  = ho;
                if (l == NLAY-1)
                    enc[((size_t)(b0+s)*SSTEP + t)*HDIM + j] = ho;
            }
            __syncthreads();
        }
    }
}

// ---------------- decoders (f32, negligible cost) ----------------

__global__ __launch_bounds__(256)
void seqdec_kernel(const float* __restrict__ enc,
                   const float* __restrict__ W1, const float* __restrict__ b1,
                   const float* __restrict__ W2, const float* __restrict__ b2,
                   const float* __restrict__ W3, const float* __restrict__ b3,
                   const float* __restrict__ W4, const float* __restrict__ b4,
                   float* __restrict__ yseq)
{
    int idx = blockIdx.x*blockDim.x + threadIdx.x;
    if (idx >= NB*SSTEP) return;
    int b = idx >> 7, s = idx & 127;
    const float* e = enc + (size_t)idx*HDIM;

    float A[8][4], Bm[8][4], Cm[8][4];
    #pragma unroll
    for (int g = 0; g < 8; ++g)
      #pragma unroll
      for (int o = 0; o < 4; ++o) {
        float acc = b1[o];
        for (int k = 0; k < 32; ++k) acc += e[g*32+k] * W1[o*32+k];
        A[g][o] = acc;
      }
    #pragma unroll
    for (int r = 0; r < 8; ++r)
      #pragma unroll
      for (int c = 0; c < 4; ++c) {
        float acc = b2[c];
        #pragma unroll
        for (int q = 0; q < 4; ++q)
            acc += A[(4*r+q)&7][(4*r+q)>>3] * W2[c*4+q];
        Bm[r][c] = acc;
      }
    #pragma unroll
    for (int r = 0; r < 8; ++r)
      #pragma unroll
      for (int c = 0; c < 4; ++c) {
        float acc = b3[c];
        #pragma unroll
        for (int q = 0; q < 4; ++q)
            acc += Bm[(4*r+q)&7][(4*r+q)>>3] * W3[c*4+q];
        Cm[r][c] = acc;
      }
    #pragma unroll
    for (int o = 0; o < 4; ++o)
      #pragma unroll
      for (int w = 0; w < 8; ++w) {
        float acc = b4[w];
        #pragma unroll
        for (int g = 0; g < 8; ++g)
            acc += Cm[(o*8+g)>>2][(o*8+g)&3] * W4[w*8+g];
        yseq[((size_t)b*LSEQ + s*8 + w)*4 + o] = acc;
      }
}

__global__ __launch_bounds__(64)
void onedec_kernel(const float* __restrict__ enc,
                   const float* __restrict__ W1, const float* __restrict__ b1,
                   const float* __restrict__ W2, const float* __restrict__ b2,
                   const float* __restrict__ W3, const float* __restrict__ b3,
                   const float* __restrict__ W4, const float* __restrict__ b4,
                   float* __restrict__ yone)
{
    int b = blockIdx.x;
    int tid = threadIdx.x;
    __shared__ float part[10][4];
    if (tid < 10) {
        int s = SSTEP - 10 + tid;
        const float* e = enc + ((size_t)b*SSTEP + s)*HDIM;
        float A[8][4], Bm[8][4], Cm[8][4];
        #pragma unroll
        for (int g = 0; g < 8; ++g)
          #pragma unroll
          for (int o = 0; o < 4; ++o) {
            float acc = b1[o];
            for (int k = 0; k < 32; ++k) acc += e[g*32+k] * W1[o*32+k];
            A[g][o] = acc;
          }
        #pragma unroll
        for (int r = 0; r < 8; ++r)
          #pragma unroll
          for (int c = 0; c < 4; ++c) {
            float acc = b2[c];
            #pragma unroll
            for (int q = 0; q < 4; ++q)
                acc += A[(4*r+q)&7][(4*r+q)>>3] * W2[c*4+q];
            Bm[r][c] = acc;
          }
        #pragma unroll
        for (int r = 0; r < 8; ++r)
          #pragma unroll
          for (int c = 0; c < 4; ++c) {
            float acc = b3[c];
            #pragma unroll
            for (int q = 0; q < 4; ++q)
                acc += Bm[(4*r+q)&7][(4*r+q)>>3] * W3[c*4+q];
            Cm[r][c] = fmaxf(acc, 0.f);   // relu
          }
        #pragma unroll
        for (int jj = 0; jj < 4; ++jj) {
            float acc = b4[jj];
            #pragma unroll
            for (int m = 0; m < 32; ++m)
                acc += Cm[m>>2][m&3] * W4[jj*32+m];
            part[tid][jj] = sigm(acc);
        }
    }
    __syncthreads();
    if (tid < 4) {
        float acc = 0.f;
        #pragma unroll
        for (int k = 0; k < 10; ++k) acc += part[k][tid];
        yone[b*4 + tid] = acc * 0.1f;
    }
}

extern "C" void kernel_launch(void* const* d_in, const int* in_sizes, int n_in,
                              void* d_out, int out_size, void* d_ws, size_t ws_size,
                              hipStream_t stream)
{
    const float* x    = (const float*)d_in[0];
    const float* Wih0 = (const float*)d_in[1];
    const float* WihR = (const float*)d_in[2];
    const float* Whh  = (const float*)d_in[3];
    const float* bih  = (const float*)d_in[4];
    const float* bhh  = (const float*)d_in[5];
    const float* h0   = (const float*)d_in[6];
    const float* aW1  = (const float*)d_in[7];
    const float* aW2  = (const float*)d_in[8];
    const float* aW3  = (const float*)d_in[9];
    const float* aW4  = (const float*)d_in[10];
    const float* sdW1 = (const float*)d_in[11];
    const float* sdb1 = (const float*)d_in[12];
    const float* sdW2 = (const float*)d_in[13];
    const float* sdb2 = (const float*)d_in[14];
    const float* sdW3 = (const float*)d_in[15];
    const float* sdb3 = (const float*)d_in[16];
    const float* sdW4 = (const float*)d_in[17];
    const float* sdb4 = (const float*)d_in[18];
    const float* odW1 = (const float*)d_in[19];
    const float* odb1 = (const float*)d_in[20];
    const float* odW2 = (const float*)d_in[21];
    const float* odb2 = (const float*)d_in[22];
    const float* odW3 = (const float*)d_in[23];
    const float* odb3 = (const float*)d_in[24];
    const float* odW4 = (const float*)d_in[25];
    const float* odb4 = (const float*)d_in[26];

    // bf16 weight segments in d_ws
    u16* w = (u16*)d_ws;
    u16* wih0b = w;                  w += N_WIH0;
    u16* wihRb = w;                  w += N_WIHR;
    u16* whhb  = w;                  w += N_WHH;
    u16* aW1b  = w;                  w += N_AW1;
    u16* aW2b  = w;                  w += N_AW2;
    u16* aW3b  = w;                  w += N_AW3;
    u16* aW4b  = w;

    #define RP(src, dst, n) hipLaunchKernelGGL(repack_kernel, dim3(((n)+255)/256), dim3(256), 0, stream, src, dst, n)
    RP(Wih0, wih0b, N_WIH0);
    RP(WihR, wihRb, N_WIHR);
    RP(Whh,  whhb,  N_WHH);
    RP(aW1,  aW1b,  N_AW1);
    RP(aW2,  aW2b,  N_AW2);
    RP(aW3,  aW3b,  N_AW3);
    RP(aW4,  aW4b,  N_AW4);
    #undef RP

    float* out  = (float*)d_out;
    float* enc  = out;                                   // [256][128][256]
    float* yseq = out + (size_t)NB*SSTEP*HDIM;           // [256][1024][4]
    float* yone = yseq + (size_t)NB*LSEQ*4;              // [256][4]

    hipLaunchKernelGGL(encoder_kernel, dim3(NBLK), dim3(TPB), 0, stream,
                       x, wih0b, wihRb, whhb, bih, bhh, h0, aW1b, aW2b, aW3b, aW4b, enc);
    hipLaunchKernelGGL(seqdec_kernel, dim3((NB*SSTEP)/256), dim3(256), 0, stream,
                       enc, sdW1, sdb1, sdW2, sdb2, sdW3, sdb3, sdW4, sdb4, yseq);
    hipLaunchKernelGGL(onedec_kernel, dim3(NB), dim3(64), 0, stream,
                       enc, odW1, odb1, odW2, odb2, odW3, odb3, odW4, odb4, yone);
}